// Round 9
// baseline (210.613 us; speedup 1.0000x reference)
//
#include <hip/hip_runtime.h>
#include <hip/hip_bf16.h>

typedef unsigned short u16;
typedef __attribute__((ext_vector_type(8))) short  bf16x8;
typedef __attribute__((ext_vector_type(8))) u16    u16x8;
typedef __attribute__((ext_vector_type(4))) float  fx4;

// flat offsets of TT cores in the packed kernel (reference iterates k=3..0 from idx 0)
#define OFF_C0 0       // core for k=3: [8 x 256]   core0[i4][a3*8+o4]
#define OFF_C1 2048    // core for k=2: [256 x 256] core1[i3*32+a3][a2*8+o3]
#define OFF_C2 67584   // core for k=1: [256 x 256] core2[i2*32+a2][a1*8+o2]
#define OFF_C3 133120  // core for k=0: [256 x 8]   core3[i1*32+a1][o1]

static __device__ __forceinline__ u16 f2bf(float f) {
  union { __hip_bfloat16 h; u16 u; } cv;
  cv.h = __float2bfloat16(f);
  return cv.u;
}
static __device__ __forceinline__ float bf2f(u16 u) {
  union { u16 u; __hip_bfloat16 h; } cv;
  cv.u = u;
  return __bfloat162float(cv.h);
}

// fused: blocks [0,8192): x fp32 -> bf16 row-major (fully coalesced); [8192,8704): W34T.
__global__ void x_and_w34T(const float* __restrict__ x, u16* __restrict__ xb,
                           const float* __restrict__ ker, float* __restrict__ w34T) {
  if (blockIdx.x < 8192) {
    int t = blockIdx.x * 256 + threadIdx.x;
    const fx4* p = (const fx4*)(x + (size_t)t * 8);
    fx4 v0 = p[0], v1 = p[1];
    u16 tmp[8];
#pragma unroll
    for (int q = 0; q < 4; ++q) tmp[q] = f2bf(v0[q]);
#pragma unroll
    for (int q = 0; q < 4; ++q) tmp[4 + q] = f2bf(v1[q]);
    *(u16x8*)(xb + (size_t)t * 8) = *(const u16x8*)tmp;
  } else {
    int t = (blockIdx.x - 8192) * 256 + threadIdx.x;   // 131072 threads
    int i34 = t & 63, c = t >> 6;
    int a2 = c >> 6, o3 = (c >> 3) & 7, o4 = c & 7;
    int i3 = i34 >> 3, i4 = i34 & 7;
    float s = 0.f;
#pragma unroll 8
    for (int a3 = 0; a3 < 32; ++a3) {
      float k1 = ker[OFF_C1 + (i3 * 32 + a3) * 256 + a2 * 8 + o3];
      float k0 = ker[OFF_C0 + i4 * 256 + a3 * 8 + o4];
      s += k1 * k0;
    }
    w34T[c * 64 + i34] = s;
  }
}

// W234t[(a1*64+o2*8+o3)*8 + o4][i234] = sum_a2 core2[i2*32+a2, a1*8+o2] * W34T[a2*64+o3*8+o4][i34]
__global__ void build_w234t2(const float* __restrict__ ker, const float* __restrict__ w34T,
                             u16* __restrict__ w234t) {
  int t = blockIdx.x * 256 + threadIdx.x;   // 131072 threads
  int i234 = t & 511, g = t >> 9;           // g = a1*8 + o3
  int a1 = g >> 3, o3 = g & 7;
  int i2 = i234 >> 6, i34 = i234 & 63;
  float acc[8][8];
#pragma unroll
  for (int a = 0; a < 8; ++a)
#pragma unroll
    for (int b = 0; b < 8; ++b) acc[a][b] = 0.f;
  for (int a2 = 0; a2 < 32; ++a2) {
    float w[8];
#pragma unroll
    for (int o4 = 0; o4 < 8; ++o4)
      w[o4] = w34T[(a2 * 64 + o3 * 8 + o4) * 64 + i34];
#pragma unroll
    for (int o2 = 0; o2 < 8; ++o2) {
      float c2 = ker[OFF_C2 + (i2 * 32 + a2) * 256 + a1 * 8 + o2];
#pragma unroll
      for (int o4 = 0; o4 < 8; ++o4) acc[o2][o4] += c2 * w[o4];
    }
  }
#pragma unroll
  for (int o2 = 0; o2 < 8; ++o2) {
    int cg = a1 * 64 + o2 * 8 + o3;
#pragma unroll
    for (int o4 = 0; o4 < 8; ++o4)
      w234t[(cg * 8 + o4) * 512 + i234] = f2bf(acc[o2][o4]);
  }
}

// Wt[j,i] -> 16x16-fragment-major wtt: flat = (kk*256 + n16)*512 + l*8 + e, where
// lane l of unit (kk,n16) holds Wt[n16*16 + (l&15)][kk*32 + (l>>4)*8 + e]  (e=0..7).
// Thread owns (j234, i234), reads each w234t element once, computes all 64 (i1,o1).
__global__ void build_wt4(const float* __restrict__ ker, const u16* __restrict__ w234t,
                          u16* __restrict__ wtt) {
  int t = blockIdx.x * 256 + threadIdx.x;   // 262144 threads
  int i234 = t & 511, j234 = t >> 9;
  float acc[8][8];
#pragma unroll
  for (int a = 0; a < 8; ++a)
#pragma unroll
    for (int b = 0; b < 8; ++b) acc[a][b] = 0.f;
  for (int a1 = 0; a1 < 32; ++a1) {
    float w = bf2f(w234t[(a1 * 512 + j234) * 512 + i234]);
#pragma unroll
    for (int i1 = 0; i1 < 8; ++i1) {
      const float* c3 = ker + OFF_C3 + (i1 * 32 + a1) * 8;
#pragma unroll
      for (int o1 = 0; o1 < 8; ++o1) acc[i1][o1] += c3[o1] * w;
    }
  }
  // j = o1*512 + j234, i = i1*512 + i234
  const int e    = i234 & 7;
  const int l    = (j234 & 15) | (((i234 >> 3) & 3) << 4);
  const int kklo = i234 >> 5;
#pragma unroll
  for (int o1 = 0; o1 < 8; ++o1) {
    const int n16 = o1 * 32 + (j234 >> 4);
#pragma unroll
    for (int i1 = 0; i1 < 8; ++i1) {
      const int kk = i1 * 16 + kklo;
      wtt[((size_t)kk * 256 + n16) * 512 + l * 8 + e] = f2bf(acc[i1][o1]);
    }
  }
}

__device__ __forceinline__ void gld16(const u16* g, u16* l) {
  __builtin_amdgcn_global_load_lds((const __attribute__((address_space(1))) void*)g,
                                   (__attribute__((address_space(3))) void*)l, 16, 0, 0);
}

// C[4096,4096] = A*Wt^T + bias. A row-major bf16 staged to LDS (R3's proven path);
// B read DIRECT global->VGPR from fragment-major wtt (1KB-contiguous per wave-read),
// prefetched 1 tile ahead. 256x256 tile, BK=32, 8 waves 2Mx4N, 8x4 frags 16x16x32.
// LDS: A only, 4 bufs x 16KB = 64KB. Per tile: 8 ds_read_b128 + 2 gld16 (t+3) +
// 4 B-global (t+1) + 32 MFMA + vmcnt(8) + one barrier.
__global__ __launch_bounds__(512, 2) void gemm_bdir(const u16* __restrict__ A, const u16* __restrict__ Bg,
                                                    const float* __restrict__ bias, float* __restrict__ C) {
  __shared__ __align__(16) u16 sh[32768];  // 4 A-buffers of 8192 elems ([256 rows][32 k])

  const int tid = threadIdx.x;
  const int lane = tid & 63;
  const int wave = tid >> 6;
  const int wm = wave >> 2, wn = wave & 3;
  const int fr = lane & 15, fg = lane >> 4;

  // XCD-aware block swizzle (256 blocks, 256%8==0)
  const int bid = blockIdx.x;
  const int wg = (bid & 7) * 32 + (bid >> 3);
  const int bm = (wg >> 4) * 256, bn = (wg & 15) * 256;

  // A staging (R3, proven 0-conflict): thread -> row tid>>2 (+128), slot tid&3;
  // LDS dest linear, global source slot pre-swizzled s ^ ((row>>1)&3).
  const int srow = tid >> 2;
  const int sco = (((tid & 3) ^ ((tid >> 3) & 3)) * 8);
  const size_t agA0 = (size_t)(bm + srow) * 4096 + sco;
  const size_t agA1 = agA0 + (size_t)128 * 4096;
  const int ldsW = wave * 512;

  // A fragment offsets within a buffer
  int aoff[8];
#pragma unroll
  for (int m = 0; m < 8; ++m) {
    const int R = wm * 128 + m * 16 + fr;
    aoff[m] = R * 32 + ((fg ^ ((R >> 1) & 3)) * 8);
  }

  // B: wave's 4 units start at n16 = bn/16 + wn*4; lane offset lane*8; tile stride 131072.
  const u16* const Bw = Bg + ((size_t)((bn >> 4) + wn * 4)) * 512 + lane * 8;

  fx4 acc[8][4];
#pragma unroll
  for (int m = 0; m < 8; ++m)
#pragma unroll
    for (int n = 0; n < 4; ++n) acc[m][n] = (fx4){0.f, 0.f, 0.f, 0.f};

#define STAGE_A(buf, tt) do { const size_t ko = (size_t)((tt) & 127) * 32; \
    u16* a_ = sh + (buf) * 8192 + ldsW; \
    gld16(A + agA0 + ko, a_); \
    gld16(A + agA1 + ko, a_ + 4096); } while (0)
#define LOADB(dst, tt) do { const size_t bo = (size_t)((tt) & 127) * 131072; \
    _Pragma("unroll") \
    for (int n_ = 0; n_ < 4; ++n_) dst[n_] = *(const bf16x8*)(Bw + bo + n_ * 512); } while (0)

  bf16x8 bva[4], bvb[4];

  // prologue: B(0) + stage A tiles 0,1,2; wait A(0)+B(0) (retire to 4 outstanding)
  LOADB(bva, 0);
  STAGE_A(0, 0);
  STAGE_A(1, 1);
  STAGE_A(2, 2);
  asm volatile("s_waitcnt vmcnt(4)" ::: "memory");
  __builtin_amdgcn_s_barrier();

#define BODY(t, bvc, bvn) do { \
    const u16* Ap = sh + ((t) & 3) * 8192; \
    LOADB(bvn, (t) + 1); \
    bf16x8 av[8]; \
    _Pragma("unroll") \
    for (int m_ = 0; m_ < 8; ++m_) av[m_] = *(const bf16x8*)(Ap + aoff[m_]); \
    STAGE_A(((t) + 3) & 3, (t) + 3); \
    __builtin_amdgcn_s_setprio(1); \
    _Pragma("unroll") \
    for (int m_ = 0; m_ < 8; ++m_) \
      _Pragma("unroll") \
      for (int n_ = 0; n_ < 4; ++n_) \
        acc[m_][n_] = __builtin_amdgcn_mfma_f32_16x16x32_bf16(av[m_], bvc[n_], acc[m_][n_], 0, 0, 0); \
    __builtin_amdgcn_s_setprio(0); \
    asm volatile("s_waitcnt vmcnt(8)" ::: "memory"); \
    __builtin_amdgcn_s_barrier(); \
  } while (0)

  for (int t = 0; t < 128; t += 2) {
    BODY(t, bva, bvb);
    BODY(t + 1, bvb, bva);
  }

  // epilogue: C/D layout col=lane&15, row=(lane>>4)*4+reg  [m89]
  const int crow0 = bm + wm * 128 + fg * 4;
  const int ccol0 = bn + wn * 64 + fr;
#pragma unroll
  for (int n = 0; n < 4; ++n) {
    const int col = ccol0 + n * 16;
    const float bvl = bias[col];
#pragma unroll
    for (int mf = 0; mf < 8; ++mf) {
      const int r0 = crow0 + mf * 16;
#pragma unroll
      for (int q = 0; q < 4; ++q)
        C[(size_t)(r0 + q) * 4096 + col] = acc[mf][n][q] + bvl;
    }
  }
#undef STAGE_A
#undef LOADB
#undef BODY
}

extern "C" void kernel_launch(void* const* d_in, const int* in_sizes, int n_in,
                              void* d_out, int out_size, void* d_ws, size_t ws_size,
                              hipStream_t stream) {
  const float* x    = (const float*)d_in[0];
  const float* ker  = (const float*)d_in[1];
  const float* bias = (const float*)d_in[2];
  float* out = (float*)d_out;

  char* ws = (char*)d_ws;
  u16*  xb    = (u16*)ws;                      // 32 MB  bf16 x, row-major
  u16*  wtt   = (u16*)(ws + 33554432);         // 32 MB  bf16 W^T, 16x16-fragment-major
  u16*  w234t = (u16*)(ws + 67108864);         // 16 MB  bf16 W234^T
  float* w34T = (float*)(ws + 83886080);       // 512 KB fp32 W34 transposed

  x_and_w34T  <<<8704, 256, 0, stream>>>(x, xb, ker, w34T);
  build_w234t2<<<512, 256, 0, stream>>>(ker, w34T, w234t);
  build_wt4   <<<1024, 256, 0, stream>>>(ker, w234t, wtt);
  gemm_bdir   <<<256, 512, 0, stream>>>(xb, wtt, bias, out);
}

// Round 10
// 192.234 us; speedup vs baseline: 1.0956x; 1.0956x over previous
//
#include <hip/hip_runtime.h>
#include <hip/hip_bf16.h>

typedef unsigned short u16;
typedef __attribute__((ext_vector_type(8))) short  bf16x8;
typedef __attribute__((ext_vector_type(8))) u16    u16x8;
typedef __attribute__((ext_vector_type(4))) float  fx4;

// flat offsets of TT cores in the packed kernel (reference iterates k=3..0 from idx 0)
#define OFF_C0 0       // core for k=3: [8 x 256]   core0[i4][a3*8+o4]
#define OFF_C1 2048    // core for k=2: [256 x 256] core1[i3*32+a3][a2*8+o3]
#define OFF_C2 67584   // core for k=1: [256 x 256] core2[i2*32+a2][a1*8+o2]
#define OFF_C3 133120  // core for k=0: [256 x 8]   core3[i1*32+a1][o1]

static __device__ __forceinline__ u16 f2bf(float f) {
  union { __hip_bfloat16 h; u16 u; } cv;
  cv.h = __float2bfloat16(f);
  return cv.u;
}
static __device__ __forceinline__ float bf2f(u16 u) {
  union { u16 u; __hip_bfloat16 h; } cv;
  cv.u = u;
  return __bfloat162float(cv.h);
}

// W34T[c][i34], c = a2*64 + o3*8 + o4 (2048 x 64 fp32)
__global__ void build_w34T(const float* __restrict__ ker, float* __restrict__ w34T) {
  int t = blockIdx.x * 256 + threadIdx.x;   // 131072 threads
  int i34 = t & 63, c = t >> 6;
  int a2 = c >> 6, o3 = (c >> 3) & 7, o4 = c & 7;
  int i3 = i34 >> 3, i4 = i34 & 7;
  float s = 0.f;
#pragma unroll 8
  for (int a3 = 0; a3 < 32; ++a3) {
    float k1 = ker[OFF_C1 + (i3 * 32 + a3) * 256 + a2 * 8 + o3];
    float k0 = ker[OFF_C0 + i4 * 256 + a3 * 8 + o4];
    s += k1 * k0;
  }
  w34T[c * 64 + i34] = s;
}

// W234t[(a1*64+o2*8+o3)*8 + o4][i234] = sum_a2 core2[i2*32+a2, a1*8+o2] * W34T[a2*64+o3*8+o4][i34]
__global__ void build_w234t2(const float* __restrict__ ker, const float* __restrict__ w34T,
                             u16* __restrict__ w234t) {
  int t = blockIdx.x * 256 + threadIdx.x;   // 131072 threads
  int i234 = t & 511, g = t >> 9;           // g = a1*8 + o3
  int a1 = g >> 3, o3 = g & 7;
  int i2 = i234 >> 6, i34 = i234 & 63;
  float acc[8][8];
#pragma unroll
  for (int a = 0; a < 8; ++a)
#pragma unroll
    for (int b = 0; b < 8; ++b) acc[a][b] = 0.f;
  for (int a2 = 0; a2 < 32; ++a2) {
    float w[8];
#pragma unroll
    for (int o4 = 0; o4 < 8; ++o4)
      w[o4] = w34T[(a2 * 64 + o3 * 8 + o4) * 64 + i34];
#pragma unroll
    for (int o2 = 0; o2 < 8; ++o2) {
      float c2 = ker[OFF_C2 + (i2 * 32 + a2) * 256 + a1 * 8 + o2];
#pragma unroll
      for (int o4 = 0; o4 < 8; ++o4) acc[o2][o4] += c2 * w[o4];
    }
  }
#pragma unroll
  for (int o2 = 0; o2 < 8; ++o2) {
    int cg = a1 * 64 + o2 * 8 + o3;
#pragma unroll
    for (int o4 = 0; o4 < 8; ++o4)
      w234t[(cg * 8 + o4) * 512 + i234] = f2bf(acc[o2][o4]);
  }
}

// Wt[j,i] row-major bf16: thread owns (j234, i234), reads each w234t element once.
__global__ void build_wt2(const float* __restrict__ ker, const u16* __restrict__ w234t,
                          u16* __restrict__ wt) {
  int t = blockIdx.x * 256 + threadIdx.x;   // 262144 threads
  int i234 = t & 511, j234 = t >> 9;
  float acc[8][8];
#pragma unroll
  for (int a = 0; a < 8; ++a)
#pragma unroll
    for (int b = 0; b < 8; ++b) acc[a][b] = 0.f;
  for (int a1 = 0; a1 < 32; ++a1) {
    float w = bf2f(w234t[(a1 * 512 + j234) * 512 + i234]);
#pragma unroll
    for (int i1 = 0; i1 < 8; ++i1) {
      const float* c3 = ker + OFF_C3 + (i1 * 32 + a1) * 8;
#pragma unroll
      for (int o1 = 0; o1 < 8; ++o1) acc[i1][o1] += c3[o1] * w;
    }
  }
#pragma unroll
  for (int o1 = 0; o1 < 8; ++o1)
#pragma unroll
    for (int i1 = 0; i1 < 8; ++i1)
      wt[(size_t)(o1 * 512 + j234) * 4096 + i1 * 512 + i234] = f2bf(acc[i1][o1]);
}

__device__ __forceinline__ void gld16(const void* g, void* l) {
  __builtin_amdgcn_global_load_lds((const __attribute__((address_space(1))) void*)g,
                                   (__attribute__((address_space(3))) void*)l, 16, 0, 0);
}

// C = x * Wt^T + bias. A = fp32 x staged DIRECTLY to LDS (no bf16 pre-pass), converted
// to bf16 fragments in-register after ds_read. B = bf16 Wt staged with R1-proven swizzle.
// 256x256 tile, BK=32, 8 waves 2Mx4N, 8x4 frags 16x16x32. LDS: 3 bufs x (A 32KB + B 16KB)
// = 144 KB. R3's free-run loop: 20 ds_read + 6 gld16 (stage t+2) + cvt + 32 MFMA +
// vmcnt(6) + one barrier.
// A swizzle (16B granules, 8 per 128B row): lds slot16 s holds global col16 s ^ (row&7);
// frag read slot = (fg*2+h) ^ (R&7) -> per b128 all 32 banks, 2 lanes/bank (free, m136).
__global__ __launch_bounds__(512, 2) void gemm_f32a(const float* __restrict__ X, const u16* __restrict__ Bt,
                                                    const float* __restrict__ bias, float* __restrict__ C) {
  __shared__ __align__(16) float shA[24576];  // 3 bufs x 8192 fp32 ([256 rows][32 k])
  __shared__ __align__(16) u16   shB[24576];  // 3 bufs x 8192 u16  ([256 rows][32 k])

  const int tid = threadIdx.x;
  const int lane = tid & 63;
  const int wave = tid >> 6;
  const int wm = wave >> 2, wn = wave & 3;
  const int fr = lane & 15, fg = lane >> 4;

  // XCD-aware block swizzle (256 blocks, 256%8==0)
  const int bid = blockIdx.x;
  const int wg = (bid & 7) * 32 + (bid >> 3);
  const int bm = (wg >> 4) * 256, bn = (wg & 15) * 256;

  // A staging: 4 gld16/thread; load L covers dest rows L*64 + (tid>>3), dest slot16 tid&7.
  // global source col16 = (tid&7) ^ (row&7)  (involution).
  size_t agA[4];
#pragma unroll
  for (int L = 0; L < 4; ++L) {
    const int r = L * 64 + (tid >> 3);
    agA[L] = (size_t)(bm + r) * 4096 + (((tid & 7) ^ (r & 7)) * 4);
  }
  // B staging: 2 gld16/thread; load L covers dest rows L*128 + (tid>>2), dest slot tid&3.
  // global source slot = (tid&3) ^ ((row>>1)&3)  (R1-proven, 0 conflicts).
  size_t agB[2];
#pragma unroll
  for (int L = 0; L < 2; ++L) {
    const int r = L * 128 + (tid >> 2);
    agB[L] = (size_t)(bn + r) * 4096 + (((tid & 3) ^ ((r >> 1) & 3)) * 8);
  }
  const int ldsWA = wave * 256;  // fp32 elems: wave-uniform dest offset per 2048-elem chunk
  const int ldsWB = wave * 512;  // u16 elems per 4096-elem chunk

  // fragment read offsets
  int aoff[8][2], boff[4];
#pragma unroll
  for (int m = 0; m < 8; ++m) {
    const int R = wm * 128 + m * 16 + fr;
#pragma unroll
    for (int h = 0; h < 2; ++h)
      aoff[m][h] = R * 32 + (((fg * 2 + h) ^ (R & 7)) * 4);   // fp32 elems
  }
#pragma unroll
  for (int n = 0; n < 4; ++n) {
    const int R = wn * 64 + n * 16 + fr;
    boff[n] = R * 32 + ((fg ^ ((R >> 1) & 3)) * 8);           // u16 elems
  }

  fx4 acc[8][4];
#pragma unroll
  for (int m = 0; m < 8; ++m)
#pragma unroll
    for (int n = 0; n < 4; ++n) acc[m][n] = (fx4){0.f, 0.f, 0.f, 0.f};

#define STAGE(buf, tt) do { const int k_ = ((tt) & 127) * 32; \
    float* a_ = shA + (buf) * 8192 + ldsWA; u16* b_ = shB + (buf) * 8192 + ldsWB; \
    gld16(X + agA[0] + k_, a_); \
    gld16(X + agA[1] + k_, a_ + 2048); \
    gld16(X + agA[2] + k_, a_ + 4096); \
    gld16(X + agA[3] + k_, a_ + 6144); \
    gld16(Bt + agB[0] + k_, b_); \
    gld16(Bt + agB[1] + k_, b_ + 4096); } while (0)

  // prologue: stage tiles 0,1 (12 loads); wait tile 0 (retire 6)
  STAGE(0, 0);
  STAGE(1, 1);
  asm volatile("s_waitcnt vmcnt(6)" ::: "memory");
  __builtin_amdgcn_s_barrier();

  int p = 0;   // buf of tile t
  for (int t = 0; t < 128; ++t) {
    const int ps = p + 2 >= 3 ? p - 1 : p + 2;   // buf of tile t+2
    const float* Ap = shA + p * 8192;
    const u16*   Bp = shB + p * 8192;

    // B fragments (4 x ds_read_b128)
    bf16x8 bv[4];
#pragma unroll
    for (int n = 0; n < 4; ++n) bv[n] = *(const bf16x8*)(Bp + boff[n]);

    // A fragments: 16 x ds_read_b128 fp32 -> convert to bf16x8 in-register
    bf16x8 av[8];
#pragma unroll
    for (int m = 0; m < 8; ++m) {
      fx4 lo = *(const fx4*)(Ap + aoff[m][0]);
      fx4 hi = *(const fx4*)(Ap + aoff[m][1]);
      u16 tmp[8];
#pragma unroll
      for (int q = 0; q < 4; ++q) tmp[q] = f2bf(lo[q]);
#pragma unroll
      for (int q = 0; q < 4; ++q) tmp[4 + q] = f2bf(hi[q]);
      av[m] = *(const bf16x8*)tmp;
    }

    STAGE(ps, t + 2);   // fire-and-forget; HBM/L2 latency hides under MFMA

    __builtin_amdgcn_s_setprio(1);
#pragma unroll
    for (int m = 0; m < 8; ++m)
#pragma unroll
      for (int n = 0; n < 4; ++n)
        acc[m][n] = __builtin_amdgcn_mfma_f32_16x16x32_bf16(av[m], bv[n], acc[m][n], 0, 0, 0);
    __builtin_amdgcn_s_setprio(0);

    // retire tile t+1's 6 loads (needed next iter); keep t+2's 6 in flight.
    asm volatile("s_waitcnt vmcnt(6)" ::: "memory");
    __builtin_amdgcn_s_barrier();
    p = p + 1 >= 3 ? 0 : p + 1;
  }

  // epilogue: C/D layout col=lane&15, row=(lane>>4)*4+reg  [m89]
  const int crow0 = bm + wm * 128 + fg * 4;
  const int ccol0 = bn + wn * 64 + fr;
#pragma unroll
  for (int n = 0; n < 4; ++n) {
    const int col = ccol0 + n * 16;
    const float bvl = bias[col];
#pragma unroll
    for (int mf = 0; mf < 8; ++mf) {
      const int r0 = crow0 + mf * 16;
#pragma unroll
      for (int q = 0; q < 4; ++q)
        C[(size_t)(r0 + q) * 4096 + col] = acc[mf][n][q] + bvl;
    }
  }
#undef STAGE
}

extern "C" void kernel_launch(void* const* d_in, const int* in_sizes, int n_in,
                              void* d_out, int out_size, void* d_ws, size_t ws_size,
                              hipStream_t stream) {
  const float* x    = (const float*)d_in[0];
  const float* ker  = (const float*)d_in[1];
  const float* bias = (const float*)d_in[2];
  float* out = (float*)d_out;

  char* ws = (char*)d_ws;
  u16*  wt    = (u16*)ws;                      // 32 MB  bf16 W^T, row-major
  u16*  w234t = (u16*)(ws + 33554432);         // 16 MB  bf16 W234^T
  float* w34T = (float*)(ws + 50331648);       // 512 KB fp32 W34 transposed

  build_w34T  <<<512, 256, 0, stream>>>(ker, w34T);
  build_w234t2<<<512, 256, 0, stream>>>(ker, w34T, w234t);
  build_wt2   <<<1024, 256, 0, stream>>>(ker, w234t, wt);
  gemm_f32a   <<<256, 512, 0, stream>>>(x, wt, bias, out);
}

// Round 11
// 182.420 us; speedup vs baseline: 1.1545x; 1.0538x over previous
//
#include <hip/hip_runtime.h>
#include <hip/hip_bf16.h>

typedef unsigned short u16;
typedef __attribute__((ext_vector_type(8))) short  bf16x8;
typedef __attribute__((ext_vector_type(8))) u16    u16x8;
typedef __attribute__((ext_vector_type(4))) float  fx4;

// flat offsets of TT cores in the packed kernel (reference iterates k=3..0 from idx 0)
#define OFF_C0 0       // core for k=3: [8 x 256]   core0[i4][a3*8+o4]
#define OFF_C1 2048    // core for k=2: [256 x 256] core1[i3*32+a3][a2*8+o3]
#define OFF_C2 67584   // core for k=1: [256 x 256] core2[i2*32+a2][a1*8+o2]
#define OFF_C3 133120  // core for k=0: [256 x 8]   core3[i1*32+a1][o1]

static __device__ __forceinline__ u16 f2bf(float f) {
  union { __hip_bfloat16 h; u16 u; } cv;
  cv.h = __float2bfloat16(f);
  return cv.u;
}
static __device__ __forceinline__ float bf2f(u16 u) {
  union { u16 u; __hip_bfloat16 h; } cv;
  cv.u = u;
  return __bfloat162float(cv.h);
}

// W34T[c][i34], c = a2*64 + o3*8 + o4 (2048 x 64 fp32)
__global__ void build_w34T(const float* __restrict__ ker, float* __restrict__ w34T) {
  int t = blockIdx.x * 256 + threadIdx.x;   // 131072 threads
  int i34 = t & 63, c = t >> 6;
  int a2 = c >> 6, o3 = (c >> 3) & 7, o4 = c & 7;
  int i3 = i34 >> 3, i4 = i34 & 7;
  float s = 0.f;
#pragma unroll 8
  for (int a3 = 0; a3 < 32; ++a3) {
    float k1 = ker[OFF_C1 + (i3 * 32 + a3) * 256 + a2 * 8 + o3];
    float k0 = ker[OFF_C0 + i4 * 256 + a3 * 8 + o4];
    s += k1 * k0;
  }
  w34T[c * 64 + i34] = s;
}

// W234t[(a1*64+o2*8+o3)*8 + o4][i234] = sum_a2 core2[i2*32+a2, a1*8+o2] * W34T[a2*64+o3*8+o4][i34]
__global__ void build_w234t2(const float* __restrict__ ker, const float* __restrict__ w34T,
                             u16* __restrict__ w234t) {
  int t = blockIdx.x * 256 + threadIdx.x;   // 131072 threads
  int i234 = t & 511, g = t >> 9;           // g = a1*8 + o3
  int a1 = g >> 3, o3 = g & 7;
  int i2 = i234 >> 6, i34 = i234 & 63;
  float acc[8][8];
#pragma unroll
  for (int a = 0; a < 8; ++a)
#pragma unroll
    for (int b = 0; b < 8; ++b) acc[a][b] = 0.f;
  for (int a2 = 0; a2 < 32; ++a2) {
    float w[8];
#pragma unroll
    for (int o4 = 0; o4 < 8; ++o4)
      w[o4] = w34T[(a2 * 64 + o3 * 8 + o4) * 64 + i34];
#pragma unroll
    for (int o2 = 0; o2 < 8; ++o2) {
      float c2 = ker[OFF_C2 + (i2 * 32 + a2) * 256 + a1 * 8 + o2];
#pragma unroll
      for (int o4 = 0; o4 < 8; ++o4) acc[o2][o4] += c2 * w[o4];
    }
  }
#pragma unroll
  for (int o2 = 0; o2 < 8; ++o2) {
    int cg = a1 * 64 + o2 * 8 + o3;
#pragma unroll
    for (int o4 = 0; o4 < 8; ++o4)
      w234t[(cg * 8 + o4) * 512 + i234] = f2bf(acc[o2][o4]);
  }
}

// Wt[j,i] row-major bf16: thread owns (j234, i234), reads each w234t element once.
__global__ void build_wt2(const float* __restrict__ ker, const u16* __restrict__ w234t,
                          u16* __restrict__ wt) {
  int t = blockIdx.x * 256 + threadIdx.x;   // 262144 threads
  int i234 = t & 511, j234 = t >> 9;
  float acc[8][8];
#pragma unroll
  for (int a = 0; a < 8; ++a)
#pragma unroll
    for (int b = 0; b < 8; ++b) acc[a][b] = 0.f;
  for (int a1 = 0; a1 < 32; ++a1) {
    float w = bf2f(w234t[(a1 * 512 + j234) * 512 + i234]);
#pragma unroll
    for (int i1 = 0; i1 < 8; ++i1) {
      const float* c3 = ker + OFF_C3 + (i1 * 32 + a1) * 8;
#pragma unroll
      for (int o1 = 0; o1 < 8; ++o1) acc[i1][o1] += c3[o1] * w;
    }
  }
#pragma unroll
  for (int o1 = 0; o1 < 8; ++o1)
#pragma unroll
    for (int i1 = 0; i1 < 8; ++i1)
      wt[(size_t)(o1 * 512 + j234) * 4096 + i1 * 512 + i234] = f2bf(acc[i1][o1]);
}

__device__ __forceinline__ void gld16(const void* g, void* l) {
  __builtin_amdgcn_global_load_lds((const __attribute__((address_space(1))) void*)g,
                                   (__attribute__((address_space(3))) void*)l, 16, 0, 0);
}

// C = x * Wt^T + bias. R3's PROVEN gemm structure (122.6us, 0 conflicts) with one change:
// A is fed from fp32 x via register-staged convert (global_load_dwordx4 -> cvt -> ds_write)
// into the IDENTICAL bf16 A-LDS layout R3 read; B staging/read unchanged (gld16 + swizzle).
// Per tile: 12 ds_read_b128 + [4 A-glb + 2 B-gld16 for t+2] + 32 MFMA + vmcnt(2) +
// 16 cvt + 2 ds_write_b128 + lgkmcnt(0) + one barrier. LDS: 3 bufs x (A16K+B16K) = 96KB.
__global__ __launch_bounds__(512, 2) void gemm_xf32(const float* __restrict__ X, const u16* __restrict__ Bt,
                                                    const float* __restrict__ bias, float* __restrict__ C) {
  __shared__ __align__(16) u16 shA[24576];  // 3 bufs x 8192 u16 ([256 rows][32 k])
  __shared__ __align__(16) u16 shB[24576];

  const int tid = threadIdx.x;
  const int lane = tid & 63;
  const int wave = tid >> 6;
  const int wm = wave >> 2, wn = wave & 3;
  const int fr = lane & 15, fg = lane >> 4;

  // XCD-aware block swizzle (256 blocks, 256%8==0)
  const int bid = blockIdx.x;
  const int wg = (bid & 7) * 32 + (bid >> 3);
  const int bm = (wg >> 4) * 256, bn = (wg & 15) * 256;

  // A reg-staged convert path. Thread owns rows r0 = tid>>2 and r1 = r0+128, slot tid&3.
  // LDS slot s of row r holds global bf16-granule g = s ^ ((r>>1)&3)  (R3 mapping).
  const int r0 = tid >> 2, r1 = r0 + 128, sl = tid & 3;
  const size_t aglb0 = (size_t)(bm + r0) * 4096 + (sl ^ ((r0 >> 1) & 3)) * 8;  // fp32 elems
  const size_t aglb1 = (size_t)(bm + r1) * 4096 + (sl ^ ((r1 >> 1) & 3)) * 8;
  const int adst0 = r0 * 32 + sl * 8;   // u16 elems within an A buffer
  const int adst1 = r1 * 32 + sl * 8;

  // B staging (R3-proven): thread -> row tid>>2 (+128), slot tid&3, pre-swizzled source.
  const int srow = tid >> 2;
  const int sco = (((tid & 3) ^ ((tid >> 3) & 3)) * 8);
  const size_t agB0 = (size_t)(bn + srow) * 4096 + sco;
  const size_t agB1 = agB0 + (size_t)128 * 4096;
  const int ldsWB = wave * 512;

  // fragment read offsets (R3-proven formulas)
  int aoff[8], boff[4];
#pragma unroll
  for (int m = 0; m < 8; ++m) {
    const int R = wm * 128 + m * 16 + fr;
    aoff[m] = R * 32 + ((fg ^ ((R >> 1) & 3)) * 8);
  }
#pragma unroll
  for (int n = 0; n < 4; ++n) {
    const int R = wn * 64 + n * 16 + fr;
    boff[n] = R * 32 + ((fg ^ ((R >> 1) & 3)) * 8);
  }

  fx4 acc[8][4];
#pragma unroll
  for (int m = 0; m < 8; ++m)
#pragma unroll
    for (int n = 0; n < 4; ++n) acc[m][n] = (fx4){0.f, 0.f, 0.f, 0.f};

  fx4 axl0, axh0, axl1, axh1;  // in-flight A fp32 (16 values)

#define ALOAD(tt) do { const int k_ = ((tt) & 127) * 32; \
    axl0 = *(const fx4*)(X + aglb0 + k_);  axh0 = *(const fx4*)(X + aglb0 + k_ + 4); \
    axl1 = *(const fx4*)(X + aglb1 + k_);  axh1 = *(const fx4*)(X + aglb1 + k_ + 4); } while (0)
#define AWRITE(buf) do { \
    u16 t0[8], t1[8]; \
    _Pragma("unroll") for (int q = 0; q < 4; ++q) { t0[q] = f2bf(axl0[q]); t0[4 + q] = f2bf(axh0[q]); \
                                                    t1[q] = f2bf(axl1[q]); t1[4 + q] = f2bf(axh1[q]); } \
    u16* ab_ = shA + (buf) * 8192; \
    *(u16x8*)(ab_ + adst0) = *(const u16x8*)t0; \
    *(u16x8*)(ab_ + adst1) = *(const u16x8*)t1; } while (0)
#define STAGE_B(buf, tt) do { const int k_ = ((tt) & 127) * 32; \
    u16* b_ = shB + (buf) * 8192 + ldsWB; \
    gld16(Bt + agB0 + k_, b_); \
    gld16(Bt + agB1 + k_, b_ + 4096); } while (0)

  // prologue: A(0)->buf0, B(0)->buf0, A(1)->buf1, B(1)->buf1; leave B(1) in flight.
  ALOAD(0);
  STAGE_B(0, 0);
  asm volatile("s_waitcnt vmcnt(2)" ::: "memory");   // A(0) regs ready
  AWRITE(0);
  ALOAD(1);
  STAGE_B(1, 1);
  asm volatile("s_waitcnt vmcnt(2)" ::: "memory");   // retires B(0) + A(1); B(1) in flight
  AWRITE(1);
  asm volatile("s_waitcnt lgkmcnt(0)" ::: "memory");
  __builtin_amdgcn_s_barrier();

  int p = 0;   // buf of tile t
  for (int t = 0; t < 128; ++t) {
    const int p2 = p + 2 >= 3 ? p - 1 : p + 2;   // buf of tile t+2
    const u16* Ap = shA + p * 8192;
    const u16* Bp = shB + p * 8192;

    // 12 fragment reads from buf p (compiler inserts counted lgkmcnt before MFMAs)
    bf16x8 av[8], bv[4];
#pragma unroll
    for (int m = 0; m < 8; ++m) av[m] = *(const bf16x8*)(Ap + aoff[m]);
#pragma unroll
    for (int n = 0; n < 4; ++n) bv[n] = *(const bf16x8*)(Bp + boff[n]);

    // issue tile t+2's loads: 4 A-global (regs) then 2 B-gld16 (LDS)
    ALOAD(t + 2);
    STAGE_B(p2, t + 2);

    __builtin_amdgcn_s_setprio(1);
#pragma unroll
    for (int m = 0; m < 8; ++m)
#pragma unroll
      for (int n = 0; n < 4; ++n)
        acc[m][n] = __builtin_amdgcn_mfma_f32_16x16x32_bf16(av[m], bv[n], acc[m][n], 0, 0, 0);
    __builtin_amdgcn_s_setprio(0);

    // outstanding: [B(t+1) x2, A(t+2) x4, B(t+2) x2] -> vmcnt(2) retires B(t+1) + A-regs.
    asm volatile("s_waitcnt vmcnt(2)" ::: "memory");
    AWRITE(p2);                                      // cvt + 2 ds_write into buf t+2
    asm volatile("s_waitcnt lgkmcnt(0)" ::: "memory");
    __builtin_amdgcn_s_barrier();
    p = p + 1 >= 3 ? 0 : p + 1;
  }

  // epilogue: C/D layout col=lane&15, row=(lane>>4)*4+reg  [m89]
  const int crow0 = bm + wm * 128 + fg * 4;
  const int ccol0 = bn + wn * 64 + fr;
#pragma unroll
  for (int n = 0; n < 4; ++n) {
    const int col = ccol0 + n * 16;
    const float bvl = bias[col];
#pragma unroll
    for (int mf = 0; mf < 8; ++mf) {
      const int r0c = crow0 + mf * 16;
#pragma unroll
      for (int q = 0; q < 4; ++q)
        C[(size_t)(r0c + q) * 4096 + col] = acc[mf][n][q] + bvl;
    }
  }
#undef ALOAD
#undef AWRITE
#undef STAGE_B
}

extern "C" void kernel_launch(void* const* d_in, const int* in_sizes, int n_in,
                              void* d_out, int out_size, void* d_ws, size_t ws_size,
                              hipStream_t stream) {
  const float* x    = (const float*)d_in[0];
  const float* ker  = (const float*)d_in[1];
  const float* bias = (const float*)d_in[2];
  float* out = (float*)d_out;

  char* ws = (char*)d_ws;
  u16*  wt    = (u16*)ws;                      // 32 MB  bf16 W^T, row-major
  u16*  w234t = (u16*)(ws + 33554432);         // 16 MB  bf16 W234^T
  float* w34T = (float*)(ws + 50331648);       // 512 KB fp32 W34 transposed

  build_w34T  <<<512, 256, 0, stream>>>(ker, w34T);
  build_w234t2<<<512, 256, 0, stream>>>(ker, w34T, w234t);
  build_wt2   <<<1024, 256, 0, stream>>>(ker, w234t, wt);
  gemm_xf32   <<<256, 512, 0, stream>>>(x, wt, bias, out);
}

// Round 12
// 180.330 us; speedup vs baseline: 1.1679x; 1.0116x over previous
//
#include <hip/hip_runtime.h>
#include <hip/hip_bf16.h>

typedef unsigned short u16;
typedef __attribute__((ext_vector_type(8))) short  bf16x8;
typedef __attribute__((ext_vector_type(8))) u16    u16x8;
typedef __attribute__((ext_vector_type(4))) float  fx4;

// flat offsets of TT cores in the packed kernel (reference iterates k=3..0 from idx 0)
#define OFF_C0 0       // core for k=3: [8 x 256]   core0[i4][a3*8+o4]
#define OFF_C1 2048    // core for k=2: [256 x 256] core1[i3*32+a3][a2*8+o3]
#define OFF_C2 67584   // core for k=1: [256 x 256] core2[i2*32+a2][a1*8+o2]
#define OFF_C3 133120  // core for k=0: [256 x 8]   core3[i1*32+a1][o1]

static __device__ __forceinline__ u16 f2bf(float f) {
  union { __hip_bfloat16 h; u16 u; } cv;
  cv.h = __float2bfloat16(f);
  return cv.u;
}
static __device__ __forceinline__ float bf2f(u16 u) {
  union { u16 u; __hip_bfloat16 h; } cv;
  cv.u = u;
  return __bfloat162float(cv.h);
}

// W34T[c][i34], c = a2*64 + o3*8 + o4 (2048 x 64 fp32)
__global__ void build_w34T(const float* __restrict__ ker, float* __restrict__ w34T) {
  int t = blockIdx.x * 256 + threadIdx.x;   // 131072 threads
  int i34 = t & 63, c = t >> 6;
  int a2 = c >> 6, o3 = (c >> 3) & 7, o4 = c & 7;
  int i3 = i34 >> 3, i4 = i34 & 7;
  float s = 0.f;
#pragma unroll 8
  for (int a3 = 0; a3 < 32; ++a3) {
    float k1 = ker[OFF_C1 + (i3 * 32 + a3) * 256 + a2 * 8 + o3];
    float k0 = ker[OFF_C0 + i4 * 256 + a3 * 8 + o4];
    s += k1 * k0;
  }
  w34T[c * 64 + i34] = s;
}

// W234t[(a1*64+o2*8+o3)*8 + o4][i234] = sum_a2 core2[i2*32+a2, a1*8+o2] * W34T[a2*64+o3*8+o4][i34]
__global__ void build_w234t2(const float* __restrict__ ker, const float* __restrict__ w34T,
                             u16* __restrict__ w234t) {
  int t = blockIdx.x * 256 + threadIdx.x;   // 131072 threads
  int i234 = t & 511, g = t >> 9;           // g = a1*8 + o3
  int a1 = g >> 3, o3 = g & 7;
  int i2 = i234 >> 6, i34 = i234 & 63;
  float acc[8][8];
#pragma unroll
  for (int a = 0; a < 8; ++a)
#pragma unroll
    for (int b = 0; b < 8; ++b) acc[a][b] = 0.f;
  for (int a2 = 0; a2 < 32; ++a2) {
    float w[8];
#pragma unroll
    for (int o4 = 0; o4 < 8; ++o4)
      w[o4] = w34T[(a2 * 64 + o3 * 8 + o4) * 64 + i34];
#pragma unroll
    for (int o2 = 0; o2 < 8; ++o2) {
      float c2 = ker[OFF_C2 + (i2 * 32 + a2) * 256 + a1 * 8 + o2];
#pragma unroll
      for (int o4 = 0; o4 < 8; ++o4) acc[o2][o4] += c2 * w[o4];
    }
  }
#pragma unroll
  for (int o2 = 0; o2 < 8; ++o2) {
    int cg = a1 * 64 + o2 * 8 + o3;
#pragma unroll
    for (int o4 = 0; o4 < 8; ++o4)
      w234t[(cg * 8 + o4) * 512 + i234] = f2bf(acc[o2][o4]);
  }
}

// Wt[j,i] row-major bf16: thread owns (j234, i234), reads each w234t element once.
__global__ void build_wt2(const float* __restrict__ ker, const u16* __restrict__ w234t,
                          u16* __restrict__ wt) {
  int t = blockIdx.x * 256 + threadIdx.x;   // 262144 threads
  int i234 = t & 511, j234 = t >> 9;
  float acc[8][8];
#pragma unroll
  for (int a = 0; a < 8; ++a)
#pragma unroll
    for (int b = 0; b < 8; ++b) acc[a][b] = 0.f;
  for (int a1 = 0; a1 < 32; ++a1) {
    float w = bf2f(w234t[(a1 * 512 + j234) * 512 + i234]);
#pragma unroll
    for (int i1 = 0; i1 < 8; ++i1) {
      const float* c3 = ker + OFF_C3 + (i1 * 32 + a1) * 8;
#pragma unroll
      for (int o1 = 0; o1 < 8; ++o1) acc[i1][o1] += c3[o1] * w;
    }
  }
#pragma unroll
  for (int o1 = 0; o1 < 8; ++o1)
#pragma unroll
    for (int i1 = 0; i1 < 8; ++i1)
      wt[(size_t)(o1 * 512 + j234) * 4096 + i1 * 512 + i234] = f2bf(acc[i1][o1]);
}

__device__ __forceinline__ void gld16(const void* g, void* l) {
  __builtin_amdgcn_global_load_lds((const __attribute__((address_space(1))) void*)g,
                                   (__attribute__((address_space(3))) void*)l, 16, 0, 0);
}

// C = x * Wt^T + bias. R3's proven structure; A fed from fp32 x via DOUBLE-BUFFERED
// register staging: A(t+2) regs loaded in tile t-1, converted+ds_written in tile t
// (latency ~600cy covered; cvt is AFTER the MFMA block, not in the read->MFMA chain).
// Per tile: 12 ds_read_b128 + [4 A-glb(t+3) + 2 B-gld16(t+2)] + 32 MFMA + vmcnt(6)
// + 16 cvt + 2 ds_write_b128 + lgkmcnt(0) + one barrier. LDS 3x(16K+16K)=96KB.
// vmcnt(6) invariant: oldest 6 outstanding = {A(t+2)x4, B(t+1)x2} regardless of
// intra-tile issue order (they are exactly the previous tile's 6 loads).
__global__ __launch_bounds__(512, 2) void gemm_xdb(const float* __restrict__ X, const u16* __restrict__ Bt,
                                                   const float* __restrict__ bias, float* __restrict__ C) {
  __shared__ __align__(16) u16 shA[24576];  // 3 bufs x 8192 u16 ([256 rows][32 k])
  __shared__ __align__(16) u16 shB[24576];

  const int tid = threadIdx.x;
  const int lane = tid & 63;
  const int wave = tid >> 6;
  const int wm = wave >> 2, wn = wave & 3;
  const int fr = lane & 15, fg = lane >> 4;

  // XCD-aware block swizzle (256 blocks, 256%8==0)
  const int bid = blockIdx.x;
  const int wg = (bid & 7) * 32 + (bid >> 3);
  const int bm = (wg >> 4) * 256, bn = (wg & 15) * 256;

  // A path: thread owns rows r0 = tid>>2, r1 = r0+128, slot sl = tid&3.
  // LDS slot s of row r holds global bf16-granule s ^ ((r>>1)&3)  (R3 content mapping).
  const int r0 = tid >> 2, r1 = r0 + 128, sl = tid & 3;
  const size_t aglb0 = (size_t)(bm + r0) * 4096 + (sl ^ ((r0 >> 1) & 3)) * 8;  // fp32 elems
  const size_t aglb1 = (size_t)(bm + r1) * 4096 + (sl ^ ((r1 >> 1) & 3)) * 8;
  const int adst0 = r0 * 32 + sl * 8;   // u16 elems within an A buffer
  const int adst1 = r1 * 32 + sl * 8;

  // B staging (R3-proven): thread -> row tid>>2 (+128), slot tid&3, pre-swizzled source.
  const int sco = (((tid & 3) ^ ((tid >> 3) & 3)) * 8);
  const size_t agB0 = (size_t)(bn + r0) * 4096 + sco;
  const size_t agB1 = agB0 + (size_t)128 * 4096;
  const int ldsWB = wave * 512;

  // fragment read offsets (R3-proven)
  int aoff[8], boff[4];
#pragma unroll
  for (int m = 0; m < 8; ++m) {
    const int R = wm * 128 + m * 16 + fr;
    aoff[m] = R * 32 + ((fg ^ ((R >> 1) & 3)) * 8);
  }
#pragma unroll
  for (int n = 0; n < 4; ++n) {
    const int R = wn * 64 + n * 16 + fr;
    boff[n] = R * 32 + ((fg ^ ((R >> 1) & 3)) * 8);
  }

  fx4 acc[8][4];
#pragma unroll
  for (int m = 0; m < 8; ++m)
#pragma unroll
    for (int n = 0; n < 4; ++n) acc[m][n] = (fx4){0.f, 0.f, 0.f, 0.f};

  // two named A-register sets (rule #20: no runtime-indexed arrays)
  fx4 s0l0, s0h0, s0l1, s0h1;
  fx4 s1l0, s1h0, s1l1, s1h1;

#define ALOAD(S, tt) do { const int k_ = ((tt) & 127) * 32; \
    S##l0 = *(const fx4*)(X + aglb0 + k_);  S##h0 = *(const fx4*)(X + aglb0 + k_ + 4); \
    S##l1 = *(const fx4*)(X + aglb1 + k_);  S##h1 = *(const fx4*)(X + aglb1 + k_ + 4); } while (0)
#define AWRITE(S, buf) do { \
    u16 t0[8], t1[8]; \
    _Pragma("unroll") for (int q = 0; q < 4; ++q) { \
      t0[q] = f2bf(S##l0[q]); t0[4 + q] = f2bf(S##h0[q]); \
      t1[q] = f2bf(S##l1[q]); t1[4 + q] = f2bf(S##h1[q]); } \
    u16* ab_ = shA + (buf) * 8192; \
    *(u16x8*)(ab_ + adst0) = *(const u16x8*)t0; \
    *(u16x8*)(ab_ + adst1) = *(const u16x8*)t1; } while (0)
#define STAGE_B(buf, tt) do { const int k_ = ((tt) & 127) * 32; \
    u16* b_ = shB + (buf) * 8192 + ldsWB; \
    gld16(Bt + agB0 + k_, b_); \
    gld16(Bt + agB1 + k_, b_ + 4096); } while (0)

  // prologue: fill bufs 0,1; leave set0 = A(2) in flight-retired, B(1) landed.
  ALOAD(s0, 0);        // 4
  STAGE_B(0, 0);       // 2
  ALOAD(s1, 1);        // 4
  STAGE_B(1, 1);       // 2  -> 12 outstanding
  asm volatile("s_waitcnt vmcnt(6)" ::: "memory");   // retire A(0), B(0)
  AWRITE(s0, 0);
  ALOAD(s0, 2);        // 4  -> [A1x4, B1x2, A2x4] = 10
  asm volatile("s_waitcnt vmcnt(6)" ::: "memory");   // retire A(1); leaves [B1x2, A2x4]
  AWRITE(s1, 1);
  asm volatile("s_waitcnt lgkmcnt(0)" ::: "memory");
  __builtin_amdgcn_s_barrier();

  int p = 0;   // buf of tile t
#define BODY(t, SW, SL) do { \
    const int p2 = p + 2 >= 3 ? p - 1 : p + 2; \
    const u16* Ap = shA + p * 8192; \
    const u16* Bp = shB + p * 8192; \
    bf16x8 av[8], bv[4]; \
    _Pragma("unroll") for (int m_ = 0; m_ < 8; ++m_) av[m_] = *(const bf16x8*)(Ap + aoff[m_]); \
    _Pragma("unroll") for (int n_ = 0; n_ < 4; ++n_) bv[n_] = *(const bf16x8*)(Bp + boff[n_]); \
    ALOAD(SL, (t) + 3); \
    STAGE_B(p2, (t) + 2); \
    __builtin_amdgcn_s_setprio(1); \
    _Pragma("unroll") for (int m_ = 0; m_ < 8; ++m_) \
      _Pragma("unroll") for (int n_ = 0; n_ < 4; ++n_) \
        acc[m_][n_] = __builtin_amdgcn_mfma_f32_16x16x32_bf16(av[m_], bv[n_], acc[m_][n_], 0, 0, 0); \
    __builtin_amdgcn_s_setprio(0); \
    asm volatile("s_waitcnt vmcnt(6)" ::: "memory"); \
    AWRITE(SW, p2); \
    asm volatile("s_waitcnt lgkmcnt(0)" ::: "memory"); \
    __builtin_amdgcn_s_barrier(); \
    p = p + 1 >= 3 ? 0 : p + 1; \
  } while (0)

  for (int t = 0; t < 128; t += 2) {
    BODY(t, s0, s1);       // AWRITE consumes A(t+2)=set0, ALOAD fills set1 with A(t+3)
    BODY(t + 1, s1, s0);
  }

  // epilogue: C/D layout col=lane&15, row=(lane>>4)*4+reg  [m89]
  const int crow0 = bm + wm * 128 + fg * 4;
  const int ccol0 = bn + wn * 64 + fr;
#pragma unroll
  for (int n = 0; n < 4; ++n) {
    const int col = ccol0 + n * 16;
    const float bvl = bias[col];
#pragma unroll
    for (int mf = 0; mf < 8; ++mf) {
      const int rr = crow0 + mf * 16;
#pragma unroll
      for (int q = 0; q < 4; ++q)
        C[(size_t)(rr + q) * 4096 + col] = acc[mf][n][q] + bvl;
    }
  }
#undef ALOAD
#undef AWRITE
#undef STAGE_B
#undef BODY
}

extern "C" void kernel_launch(void* const* d_in, const int* in_sizes, int n_in,
                              void* d_out, int out_size, void* d_ws, size_t ws_size,
                              hipStream_t stream) {
  const float* x    = (const float*)d_in[0];
  const float* ker  = (const float*)d_in[1];
  const float* bias = (const float*)d_in[2];
  float* out = (float*)d_out;

  char* ws = (char*)d_ws;
  u16*  wt    = (u16*)ws;                      // 32 MB  bf16 W^T, row-major
  u16*  w234t = (u16*)(ws + 33554432);         // 16 MB  bf16 W234^T
  float* w34T = (float*)(ws + 50331648);       // 512 KB fp32 W34 transposed

  build_w34T  <<<512, 256, 0, stream>>>(ker, w34T);
  build_w234t2<<<512, 256, 0, stream>>>(ker, w34T, w234t);
  build_wt2   <<<1024, 256, 0, stream>>>(ker, w234t, wt);
  gemm_xdb    <<<256, 512, 0, stream>>>(x, wt, bias, out);
}